// Round 1
// baseline (1019.776 us; speedup 1.0000x reference)
//
#include <hip/hip_runtime.h>

// MultiDense: y[b,n,o] = sum_i x[b,n,i]*A[0,n,o,i] + Bp[0,n,o]
// B_SZ=2048, NSPLIT=256, OUT=256, IN=256. All fp32 in/out; bf16 MFMA compute.

#define B_SZ   2048
#define NS     256
#define OUTD   256
#define IND    256

#define MT     64     // M tile per block
#define BK     32     // K step (one mfma_16x16x32 per step)
#define LDK    40     // padded LDS row pitch (bf16 elems): 80B rows -> <=2-way bank aliasing

typedef __bf16 bf16x8 __attribute__((ext_vector_type(8)));
typedef __bf16 bf16x4 __attribute__((ext_vector_type(4)));
typedef float  floatx4 __attribute__((ext_vector_type(4)));

__device__ inline bf16x4 cvt4(floatx4 v) {
    bf16x4 r;
    r[0] = (__bf16)v[0];
    r[1] = (__bf16)v[1];
    r[2] = (__bf16)v[2];
    r[3] = (__bf16)v[3];
    return r;
}

__global__ __launch_bounds__(256, 3)
void md_kernel(const float* __restrict__ x,
               const float* __restrict__ A,
               const float* __restrict__ Bp,
               float* __restrict__ out) {
    __shared__ __bf16 Xs[MT * LDK];     // 64 rows (m) x 32 k  (5.0 KB)
    __shared__ __bf16 As[OUTD * LDK];   // 256 rows (o) x 32 k (20 KB)
    __shared__ float  bias_s[OUTD];     // 1 KB

    const int bid  = blockIdx.x;
    // XCD swizzle: bid%8 ~ XCD; give each XCD a contiguous band of 32 groups,
    // with the 32 M-tiles of one group consecutive -> A_n stays hot in that XCD's L2.
    const int batch = (bid & 7) * 32 + (bid >> 8);   // group n, 0..255
    const int mtile = (bid >> 3) & 31;               // 0..31
    const int m0    = mtile * MT;

    const int t    = threadIdx.x;
    const int wid  = t >> 6;        // wave 0..3 -> n-slab
    const int lane = t & 63;
    const int l15  = lane & 15;
    const int lq   = lane >> 4;     // quad 0..3

    bias_s[t] = Bp[batch * OUTD + t];

    const float* xg = x + (size_t)m0 * (NS * IND) + (size_t)batch * IND; // row stride NS*IND
    const float* Ag = A + (size_t)batch * OUTD * IND;                    // row stride IND

    floatx4 acc[4][4];
#pragma unroll
    for (int i = 0; i < 4; ++i)
#pragma unroll
        for (int j = 0; j < 4; ++j)
            acc[i][j] = (floatx4){0.f, 0.f, 0.f, 0.f};

    // staging decomposition: flat float4 index f -> row = f>>3, k4 = (f&7)*4
    const int r_lo = t >> 3;         // 0..31
    const int k4   = (t & 7) * 4;    // 0,4,...,28

#pragma unroll 1
    for (int kt = 0; kt < IND / BK; ++kt) {
        const int kbase = kt * BK;
        // ---- stage X tile: 64 rows x 32 k = 512 float4, 2 per thread ----
#pragma unroll
        for (int j = 0; j < 2; ++j) {
            const int row = j * 32 + r_lo;
            floatx4 v = *(const floatx4*)(xg + (size_t)row * (NS * IND) + kbase + k4);
            *(bf16x4*)(&Xs[row * LDK + k4]) = cvt4(v);
        }
        // ---- stage A tile: 256 rows x 32 k = 2048 float4, 8 per thread ----
#pragma unroll
        for (int j = 0; j < 8; ++j) {
            const int row = j * 32 + r_lo;
            floatx4 v = *(const floatx4*)(Ag + (size_t)row * IND + kbase + k4);
            *(bf16x4*)(&As[row * LDK + k4]) = cvt4(v);
        }
        __syncthreads();

        // ---- fragments + MFMA: wave computes 64(m) x 64(n) ----
        bf16x8 a_frag[4], b_frag[4];
#pragma unroll
        for (int i = 0; i < 4; ++i)
            a_frag[i] = *(const bf16x8*)(&Xs[(i * 16 + l15) * LDK + lq * 8]);
#pragma unroll
        for (int j = 0; j < 4; ++j)
            b_frag[j] = *(const bf16x8*)(&As[(wid * 64 + j * 16 + l15) * LDK + lq * 8]);

#pragma unroll
        for (int i = 0; i < 4; ++i)
#pragma unroll
            for (int j = 0; j < 4; ++j)
                acc[i][j] = __builtin_amdgcn_mfma_f32_16x16x32_bf16(
                    a_frag[i], b_frag[j], acc[i][j], 0, 0, 0);

        __syncthreads();
    }

    // ---- epilogue: D frag layout col = lane&15, row = (lane>>4)*4 + reg ----
    float* og = out + (size_t)m0 * (NS * OUTD) + (size_t)batch * OUTD;
#pragma unroll
    for (int i = 0; i < 4; ++i) {
#pragma unroll
        for (int j = 0; j < 4; ++j) {
            const int o = wid * 64 + j * 16 + l15;
            const float b = bias_s[o];
#pragma unroll
            for (int r = 0; r < 4; ++r) {
                const int bm = i * 16 + lq * 4 + r;   // local m row
                og[(size_t)bm * (NS * OUTD) + o] = acc[i][j][r] + b;
            }
        }
    }
}

extern "C" void kernel_launch(void* const* d_in, const int* in_sizes, int n_in,
                              void* d_out, int out_size, void* d_ws, size_t ws_size,
                              hipStream_t stream) {
    const float* x  = (const float*)d_in[0];
    const float* A  = (const float*)d_in[1];
    const float* Bp = (const float*)d_in[2];
    float* out = (float*)d_out;

    dim3 grid((B_SZ / MT) * NS);   // 32 m-tiles * 256 groups = 8192 blocks
    dim3 block(256);
    hipLaunchKernelGGL(md_kernel, grid, block, 0, stream, x, A, Bp, out);
}